// Round 4
// baseline (159928.894 us; speedup 1.0000x reference)
//
#include <hip/hip_runtime.h>
#include <math.h>

#define Bb 4
#define Tt 4096
#define Ee 2048
#define Dd 1024
#define G4 4096        // 4*D gate rows
#define TS 256         // timesteps per slab
#define NSLAB 16

// ---- bf16 helpers (storage-only; all math fp32) ---------------------------
__device__ __forceinline__ float bflo(unsigned int u) {
    union { unsigned int i; float f; } c; c.i = u << 16; return c.f;
}
__device__ __forceinline__ float bfhi(unsigned int u) {
    union { unsigned int i; float f; } c; c.i = u & 0xffff0000u; return c.f;
}
__device__ __forceinline__ float bf1(unsigned short u) {
    union { unsigned int i; float f; } c; c.i = ((unsigned int)u) << 16; return c.f;
}
__device__ __forceinline__ unsigned short f2bf(float f) {
    union { float f; unsigned int i; } c; c.f = f;
    unsigned int x = c.i;
    return (unsigned short)((x + 0x7fffu + ((x >> 16) & 1u)) >> 16);   // RNE
}

// ---------------------------------------------------------------------------
// GEMM: gx[b][s][n] = sum_k A(b,s,k) * Wx[n][k] + (bx[n]+bh[n])
// M = Bb*TS = 1024, N = 4096, K = 2048.
// A virtual: layer0 = emb[tokens[...]] (fp32); layer1 = concat(hL[t], hR[T-1-t]) (bf16).
// ---------------------------------------------------------------------------
#define BM 128
#define BN 128
#define BK 16

__global__ __launch_bounds__(256)
void gemm_gx(const float* __restrict__ Wx,
             const float* __restrict__ bx, const float* __restrict__ bh,
             const int* __restrict__ tokens, const float* __restrict__ emb,
             const unsigned short* __restrict__ hprevb,  // [2][Bb][Tt][Dd] bf16 (layer 1)
             float* __restrict__ gx,                     // [Bb][TS][G4] this dir
             int layer, int dir, int slab0)
{
    __shared__ float As[BK][BM + 4];
    __shared__ float Bs[BK][BN + 4];
    int tid = threadIdx.x;
    int m0 = blockIdx.x * BM;
    int n0 = blockIdx.y * BN;
    int tx = tid & 15, ty = tid >> 4;
    int sm = tid >> 1;           // staging row 0..127
    int sk = (tid & 1) * 8;      // staging k offset 0 or 8

    int m = m0 + sm;
    int b = m >> 8;
    int sl = m & 255;
    int sg = slab0 + sl;
    int t = (dir == 0) ? sg : (Tt - 1 - sg);
    const float* arow0 = nullptr;
    const unsigned short* arow0b = nullptr;
    const unsigned short* arow1b = nullptr;
    if (layer == 0) {
        arow0 = emb + (size_t)tokens[b * Tt + t] * Ee;
    } else {
        arow0b = hprevb + (((size_t)(0 * Bb + b)) * Tt + t) * Dd;              // hL[t]
        arow1b = hprevb + (((size_t)(1 * Bb + b)) * Tt + (Tt - 1 - t)) * Dd;   // hR[T-1-t]
    }
    const float* brow = Wx + (size_t)(n0 + sm) * Ee;

    float acc[8][8];
    #pragma unroll
    for (int i = 0; i < 8; ++i)
        #pragma unroll
        for (int j = 0; j < 8; ++j) acc[i][j] = 0.f;

    for (int k0 = 0; k0 < Ee; k0 += BK) {
        int ka = k0 + sk;
        float4 a0, a1, b0, b1;
        if (layer == 0) {
            a0 = *(const float4*)(arow0 + ka);
            a1 = *(const float4*)(arow0 + ka + 4);
        } else {
            // 8-elem bf16 chunk; ka%8==0, Dd%8==0 -> never crosses concat seam
            const unsigned short* p = (ka < Dd) ? (arow0b + ka) : (arow1b + (ka - Dd));
            uint4 r = *(const uint4*)p;
            a0.x = bflo(r.x); a0.y = bfhi(r.x); a0.z = bflo(r.y); a0.w = bfhi(r.y);
            a1.x = bflo(r.z); a1.y = bfhi(r.z); a1.z = bflo(r.w); a1.w = bfhi(r.w);
        }
        b0 = *(const float4*)(brow + ka);
        b1 = *(const float4*)(brow + ka + 4);
        __syncthreads();
        As[sk+0][sm] = a0.x; As[sk+1][sm] = a0.y; As[sk+2][sm] = a0.z; As[sk+3][sm] = a0.w;
        As[sk+4][sm] = a1.x; As[sk+5][sm] = a1.y; As[sk+6][sm] = a1.z; As[sk+7][sm] = a1.w;
        Bs[sk+0][sm] = b0.x; Bs[sk+1][sm] = b0.y; Bs[sk+2][sm] = b0.z; Bs[sk+3][sm] = b0.w;
        Bs[sk+4][sm] = b1.x; Bs[sk+5][sm] = b1.y; Bs[sk+6][sm] = b1.z; Bs[sk+7][sm] = b1.w;
        __syncthreads();
        #pragma unroll
        for (int k = 0; k < BK; ++k) {
            float a[8], bbv[8];
            *(float4*)&a[0]   = *(const float4*)&As[k][ty*8];
            *(float4*)&a[4]   = *(const float4*)&As[k][ty*8+4];
            *(float4*)&bbv[0] = *(const float4*)&Bs[k][tx*8];
            *(float4*)&bbv[4] = *(const float4*)&Bs[k][tx*8+4];
            #pragma unroll
            for (int i = 0; i < 8; ++i)
                #pragma unroll
                for (int j = 0; j < 8; ++j)
                    acc[i][j] = fmaf(a[i], bbv[j], acc[i][j]);
        }
    }
    float bsum[8];
    #pragma unroll
    for (int j = 0; j < 8; ++j) {
        int n = n0 + tx*8 + j;
        bsum[j] = bx[n] + bh[n];
    }
    #pragma unroll
    for (int i = 0; i < 8; ++i) {
        int mm = m0 + ty*8 + i;
        int bo = mm >> 8;
        int so = mm & 255;
        float* orow = gx + (((size_t)bo * TS + so) * G4) + n0 + tx*8;
        float4 o0 = make_float4(acc[i][0]+bsum[0], acc[i][1]+bsum[1], acc[i][2]+bsum[2], acc[i][3]+bsum[3]);
        float4 o1 = make_float4(acc[i][4]+bsum[4], acc[i][5]+bsum[5], acc[i][6]+bsum[6], acc[i][7]+bsum[7]);
        *(float4*)orow     = o0;
        *(float4*)(orow+4) = o1;
    }
}

// ---------------------------------------------------------------------------
// Software per-dir-group barrier (128 blocks). Monotonic counter, no reset.
// Release: fetch_add(agent) after __syncthreads (all waves' stores drained to
// L2; agent-release writes back L2 to the coherence point). Acquire: fence
// (buffer_inv) so post-barrier loads fetch fresh data. Bounded spin: on
// pathological stall we break (wrong answer, but the container survives).
// ---------------------------------------------------------------------------
__device__ __forceinline__ void group_barrier(unsigned int* cnt, unsigned int target)
{
    __syncthreads();
    if (threadIdx.x == 0) {
        __hip_atomic_fetch_add(cnt, 1u, __ATOMIC_RELEASE, __HIP_MEMORY_SCOPE_AGENT);
        long long spins = 0;
        while (__hip_atomic_load(cnt, __ATOMIC_RELAXED, __HIP_MEMORY_SCOPE_AGENT) < target) {
            __builtin_amdgcn_s_sleep(1);
            if (++spins > (1LL << 27)) break;   // ~10s safety valve
        }
        __builtin_amdgcn_fence(__ATOMIC_ACQUIRE, "agent");
    }
    __syncthreads();
}

// ---------------------------------------------------------------------------
// Persistent LSTM scan over TS steps, one software barrier per step.
// 256 WGs x 256 threads, 1 block/CU -> all co-resident by construction.
// WG -> dir = wg>>7, 8 units x 4 gates (32 Whh rows), register-resident.
// Recurrent h: fp32 parity ping-pong (parity sg&1). Archival h: bf16 hout.
// ---------------------------------------------------------------------------
__global__ __launch_bounds__(256, 1)
void lstm_scan(const float* __restrict__ Whh,        // [L][2][G4][Dd]
               const float* __restrict__ gx,         // [2][Bb][TS][G4]
               float* __restrict__ cbuf,             // [2][Bb][Dd]
               float* __restrict__ hping,            // [2 parity][2 dir][Bb][Dd] fp32
               unsigned short* __restrict__ hout,    // [2][Bb][Tt][Dd] bf16
               unsigned int* __restrict__ barcnt,    // [2 dirs x 16-uint stride]
               int layer, int slab0, int nsteps, unsigned int base)
{
    __shared__ float hsh[Bb][Dd];        // h_{t-1}, this dir (16 KB)
    __shared__ float gvsh[4][8][Bb];     // [gate][uu][b]
    __shared__ float csh[8][Bb];         // c carry [uu][b]

    int wg = blockIdx.x;
    int dir = wg >> 7;
    int ublk = wg & 127;
    int u0 = ublk * 8;
    int tid = threadIdx.x;
    int wv = tid >> 6;        // gate index (one wave per gate)
    int ln = tid & 63;
    unsigned int* cnt = barcnt + dir * 16;   // 64B-separated counters

    // Whh slice -> registers: rows = gate wv, units u0..u0+7, k = j4*256 + ln*4
    float4 wreg[8][4];
    {
        const float* wbase = Whh + (((size_t)(layer*2 + dir) * G4) + wv*Dd + u0) * Dd;
        #pragma unroll
        for (int rr = 0; rr < 8; ++rr)
            #pragma unroll
            for (int j4 = 0; j4 < 4; ++j4)
                wreg[rr][j4] = *(const float4*)(wbase + (size_t)rr*Dd + j4*256 + ln*4);
    }
    if (tid < 32) {
        int uu = tid >> 2, b = tid & 3;
        csh[uu][b] = (slab0 == 0) ? 0.f : cbuf[(dir*Bb + b)*Dd + u0 + uu];
    }
    // csh touched only by the same (tid<32) threads before the first stage sync.

    for (int s = 0; s < nsteps; ++s) {
        int sg = slab0 + s;
        // stage h_{sg-1} (parity (sg-1)&1) for this dir
        const float* hsrc = hping + (size_t)((((sg ^ 1) & 1) * 2 + dir)) * (Bb * Dd);
        #pragma unroll
        for (int q = 0; q < 4; ++q) {
            int f = tid + 256*q;          // float4 index 0..1023
            int b = f >> 8, k4 = f & 255;
            float4 v = make_float4(0.f, 0.f, 0.f, 0.f);
            if (sg > 0)
                v = *(const float4*)(hsrc + (size_t)b * Dd + k4 * 4);
            *(float4*)&hsh[b][k4*4] = v;
        }
        __syncthreads();

        // partial dots: 8 rows x 4 batches over this lane's 16 k-positions
        float acc[8][4];
        #pragma unroll
        for (int rr = 0; rr < 8; ++rr)
            #pragma unroll
            for (int b = 0; b < 4; ++b) acc[rr][b] = 0.f;
        #pragma unroll
        for (int j4 = 0; j4 < 4; ++j4) {
            float4 h4[4];
            #pragma unroll
            for (int b = 0; b < 4; ++b)
                h4[b] = *(const float4*)&hsh[b][j4*256 + ln*4];
            #pragma unroll
            for (int rr = 0; rr < 8; ++rr) {
                float4 w4 = wreg[rr][j4];
                #pragma unroll
                for (int b = 0; b < 4; ++b) {
                    acc[rr][b] = fmaf(w4.x, h4[b].x, acc[rr][b]);
                    acc[rr][b] = fmaf(w4.y, h4[b].y, acc[rr][b]);
                    acc[rr][b] = fmaf(w4.z, h4[b].z, acc[rr][b]);
                    acc[rr][b] = fmaf(w4.w, h4[b].w, acc[rr][b]);
                }
            }
        }
        // 64-lane butterfly reduction
        #pragma unroll
        for (int off = 32; off > 0; off >>= 1)
            #pragma unroll
            for (int rr = 0; rr < 8; ++rr)
                #pragma unroll
                for (int b = 0; b < 4; ++b)
                    acc[rr][b] += __shfl_xor(acc[rr][b], off, 64);
        if (ln < 32) {
            int rr = ln >> 2, b = ln & 3;
            float gxv = gx[(((size_t)(dir*Bb + b))*TS + s)*G4 + wv*Dd + u0 + rr];
            gvsh[wv][rr][b] = acc[rr][b] + gxv;
        }
        __syncthreads();

        if (tid < 32) {
            int uu = tid >> 2, b = tid & 3;
            float xi = gvsh[0][uu][b];
            float xg = gvsh[1][uu][b];
            float xf = gvsh[2][uu][b];
            float xo = gvsh[3][uu][b];
            float iv = 1.f / (1.f + expf(-xi));
            float gg = tanhf(xg);
            float fv = 1.f / (1.f + expf(-xf));
            float ov = 1.f / (1.f + expf(-xo));
            float c = fv * csh[uu][b] + iv * gg;
            float h = ov * tanhf(c);
            csh[uu][b] = c;
            hping[((size_t)((sg & 1) * 2 + dir) * Bb + b) * Dd + u0 + uu] = h;
            hout[(((size_t)(dir*Bb + b))*Tt + sg)*Dd + u0 + uu] = f2bf(h);
        }
        group_barrier(cnt, base + (unsigned int)(s + 1) * 128u);
    }
    if (tid < 32) {
        int uu = tid >> 2, b = tid & 3;
        cbuf[(dir*Bb + b)*Dd + u0 + uu] = csh[uu][b];
    }
}

// ---------------------------------------------------------------------------
// Tail: attention + projection (hfin is bf16)
// ---------------------------------------------------------------------------
__global__ __launch_bounds__(256)
void attn_w_kernel(const unsigned short* __restrict__ hfin, float* __restrict__ w)
{
    int b = blockIdx.x >> 4;
    int t0 = (blockIdx.x & 15) * 256;
    __shared__ float hL[Dd], hR[Dd];
    for (int i = threadIdx.x; i < Dd; i += 256) {
        hL[i] = bf1(hfin[(((size_t)0*Bb + b)*Tt + (Tt-1))*Dd + i]);
        hR[i] = bf1(hfin[(((size_t)1*Bb + b)*Tt + (Tt-1))*Dd + i]);
    }
    __syncthreads();
    int t = t0 + threadIdx.x;
    const unsigned short* rL = hfin + (((size_t)0*Bb + b)*Tt + t)*Dd;
    const unsigned short* rR = hfin + (((size_t)1*Bb + b)*Tt + t)*Dd;
    float acc = 0.f;
    for (int k = 0; k < Dd; k += 8) {
        uint4 a = *(const uint4*)(rL + k);
        uint4 c = *(const uint4*)(rR + k);
        acc += bflo(a.x)*hL[k]   + bfhi(a.x)*hL[k+1] + bflo(a.y)*hL[k+2] + bfhi(a.y)*hL[k+3];
        acc += bflo(a.z)*hL[k+4] + bfhi(a.z)*hL[k+5] + bflo(a.w)*hL[k+6] + bfhi(a.w)*hL[k+7];
        acc += bflo(c.x)*hR[k]   + bfhi(c.x)*hR[k+1] + bflo(c.y)*hR[k+2] + bfhi(c.y)*hR[k+3];
        acc += bflo(c.z)*hR[k+4] + bfhi(c.z)*hR[k+5] + bflo(c.w)*hR[k+6] + bfhi(c.w)*hR[k+7];
    }
    w[b*Tt + t] = acc * (1.0f / 64.0f);   // 1/sqrt(4096)
}

__global__ __launch_bounds__(256)
void softmax_kernel(const float* __restrict__ w, float* __restrict__ att)
{
    int b = blockIdx.x;
    __shared__ float red[256];
    int tid = threadIdx.x;
    float mx = -1e30f;
    for (int t = tid; t < Tt; t += 256) mx = fmaxf(mx, w[b*Tt + t]);
    red[tid] = mx; __syncthreads();
    for (int st = 128; st > 0; st >>= 1) {
        if (tid < st) red[tid] = fmaxf(red[tid], red[tid + st]);
        __syncthreads();
    }
    mx = red[0]; __syncthreads();
    float sum = 0.f;
    for (int t = tid; t < Tt; t += 256) sum += expf(w[b*Tt + t] - mx);
    red[tid] = sum; __syncthreads();
    for (int st = 128; st > 0; st >>= 1) {
        if (tid < st) red[tid] += red[tid + st];
        __syncthreads();
    }
    sum = red[0];
    float inv = 1.f / sum;
    for (int t = tid; t < Tt; t += 256) att[b*Tt + t] = expf(w[b*Tt + t] - mx) * inv;
}

__global__ __launch_bounds__(256)
void ctxt_kernel(const float* __restrict__ att, const unsigned short* __restrict__ hfin,
                 float* __restrict__ ctxt)
{
    int dir = blockIdx.x >> 4;
    int b = (blockIdx.x >> 2) & 3;
    int k0 = (blockIdx.x & 3) * 256;
    __shared__ float attS[Tt];
    for (int i = threadIdx.x; i < Tt; i += 256) attS[i] = att[b*Tt + i];
    __syncthreads();
    int k = k0 + threadIdx.x;
    const unsigned short* base = hfin + (((size_t)dir*Bb + b)*Tt)*Dd + k;
    float acc = 0.f;
    for (int t = 0; t < Tt; ++t)
        acc = fmaf(attS[t], bf1(base[(size_t)t * Dd]), acc);
    ctxt[((size_t)dir*Bb + b)*Dd + k] = acc;
}

__global__ __launch_bounds__(256)
void final_kernel(const float* __restrict__ ctxt, const float* __restrict__ WcyL,
                  const float* __restrict__ WcyR, float* __restrict__ out)
{
    __shared__ float red[256];
    int tid = threadIdx.x;
    int g = tid >> 5;
    int l = tid & 31;
    int b = g >> 1, m = g & 1;
    float acc = 0.f;
    for (int k = l; k < Dd; k += 32)
        acc += WcyL[m*Dd + k] * ctxt[((size_t)0*Bb + b)*Dd + k]
             + WcyR[m*Dd + k] * ctxt[((size_t)1*Bb + b)*Dd + k];
    red[tid] = acc; __syncthreads();
    for (int st = 16; st > 0; st >>= 1) {
        if (l < st) red[tid] += red[tid + st];
        __syncthreads();
    }
    if (l == 0) out[b*2 + m] = red[tid];
}

// Diagnostic sentinel: distinguishable failure modes in absmax.
__global__ void sentinel_kernel(float* out, int n, float v)
{
    int i = blockIdx.x * blockDim.x + threadIdx.x;
    if (i < n) out[i] = v;
}

// ---------------------------------------------------------------------------
extern "C" void kernel_launch(void* const* d_in, const int* in_sizes, int n_in,
                              void* d_out, int out_size, void* d_ws, size_t ws_size,
                              hipStream_t stream)
{
    const int*   tokens = (const int*)d_in[0];
    const float* emb  = (const float*)d_in[1];
    const float* Wxh  = (const float*)d_in[2];
    const float* Whh  = (const float*)d_in[3];
    const float* bxh  = (const float*)d_in[4];
    const float* bhh  = (const float*)d_in[5];
    const float* WcyL = (const float*)d_in[6];
    const float* WcyR = (const float*)d_in[7];
    float* out = (float*)d_out;

    // Workspace layout (floats), then bf16 h arrays, then barrier counters.
    const size_t gx_f    = (size_t)2 * Bb * TS * G4;        // 8,388,608
    const size_t hping_f = (size_t)2 * 2 * Bb * Dd;         // 16,384
    const size_t cbuf_f  = (size_t)2 * Bb * Dd;             // 8,192
    const size_t wbuf_f  = (size_t)Bb * Tt;                 // 16,384
    const size_t attb_f  = (size_t)Bb * Tt;                 // 16,384
    const size_t ctxt_f  = (size_t)2 * Bb * Dd;             // 8,192
    const size_t h_e     = (size_t)2 * Bb * Tt * Dd;        // bf16 elems each
    const size_t need_bytes = (gx_f + hping_f + cbuf_f + wbuf_f + attb_f + ctxt_f) * 4
                            + 2 * h_e * 2 + 256;            // ~168 MiB
    if (ws_size < need_bytes) {
        sentinel_kernel<<<1, 64, 0, stream>>>(out, out_size, 1.0e6f);  // ws too small
        return;
    }
    float* ws    = (float*)d_ws;
    float* gx    = ws;
    float* hping = gx + gx_f;
    float* cbuf  = hping + hping_f;
    float* wbuf  = cbuf + cbuf_f;
    float* attb  = wbuf + wbuf_f;
    float* ctxt  = attb + attb_f;
    unsigned short* hA = (unsigned short*)(ctxt + ctxt_f);  // layer0 h bf16
    unsigned short* hB = hA + h_e;                          // layer1 h bf16
    unsigned int* barcnt = (unsigned int*)(hB + h_e);       // 2 x 16 uints

    // zero the barrier counters (ws is re-poisoned before every call)
    hipMemsetAsync(barcnt, 0, 256, stream);

    unsigned int launch_idx = 0;
    for (int layer = 0; layer < 2; ++layer) {
        unsigned short* hout = (layer == 0) ? hA : hB;
        for (int slab = 0; slab < NSLAB; ++slab) {
            int slab0 = slab * TS;
            for (int dir = 0; dir < 2; ++dir) {
                const float* Wx = Wxh + (size_t)(layer*2 + dir) * G4 * Ee;
                const float* bx = bxh + (size_t)(layer*2 + dir) * G4;
                const float* bh = bhh + (size_t)(layer*2 + dir) * G4;
                gemm_gx<<<dim3(8, 32), 256, 0, stream>>>(
                    Wx, bx, bh, tokens, emb, hA,
                    gx + (size_t)dir * Bb * TS * G4, layer, dir, slab0);
            }
            unsigned int base = launch_idx * (unsigned int)TS * 128u;
            lstm_scan<<<256, 256, 0, stream>>>(Whh, gx, cbuf, hping, hout,
                                               barcnt, layer, slab0, TS, base);
            ++launch_idx;
        }
    }
    attn_w_kernel<<<Bb*16, 256, 0, stream>>>(hB, wbuf);
    softmax_kernel<<<Bb, 256, 0, stream>>>(wbuf, attb);
    ctxt_kernel<<<32, 256, 0, stream>>>(attb, hB, ctxt);
    final_kernel<<<1, 256, 0, stream>>>(ctxt, WcyL, WcyR, out);
}

// Round 5
// 104601.367 us; speedup vs baseline: 1.5289x; 1.5289x over previous
//
#include <hip/hip_runtime.h>
#include <math.h>

#define Bb 4
#define Tt 4096
#define Ee 2048
#define Dd 1024
#define G4 4096        // 4*D gate rows
#define TS 256         // timesteps per slab
#define NSLAB 16

// ---- bf16 helpers (storage-only; all math fp32) ---------------------------
__device__ __forceinline__ float bflo(unsigned int u) {
    union { unsigned int i; float f; } c; c.i = u << 16; return c.f;
}
__device__ __forceinline__ float bfhi(unsigned int u) {
    union { unsigned int i; float f; } c; c.i = u & 0xffff0000u; return c.f;
}
__device__ __forceinline__ float bf1(unsigned short u) {
    union { unsigned int i; float f; } c; c.i = ((unsigned int)u) << 16; return c.f;
}
__device__ __forceinline__ unsigned short f2bf(float f) {
    union { float f; unsigned int i; } c; c.f = f;
    unsigned int x = c.i;
    return (unsigned short)((x + 0x7fffu + ((x >> 16) & 1u)) >> 16);   // RNE
}

// ---------------------------------------------------------------------------
// GEMM: gx[dir][b][s][n] = sum_k A(dir,b,s,k) * Wx[dir][n][k] + (bx+bh)[dir][n]
// Both dirs in ONE launch: blockIdx.z = dir  -> 512 blocks = 2 blocks/CU.
// M = Bb*TS = 1024, N = 4096, K = 2048.
// A virtual: layer0 = emb[tokens[...]] (fp32); layer1 = concat(hL[t], hR[T-1-t]) (bf16).
// ---------------------------------------------------------------------------
#define BM 128
#define BN 128
#define BK 16

__global__ __launch_bounds__(256)
void gemm_gx(const float* __restrict__ Wxh,
             const float* __restrict__ bxh, const float* __restrict__ bhh,
             const int* __restrict__ tokens, const float* __restrict__ emb,
             const unsigned short* __restrict__ hprevb,  // [2][Bb][Tt][Dd] bf16 (layer 1)
             float* __restrict__ gx,                     // [2][Bb][TS][G4]
             int layer, int slab0)
{
    __shared__ float As[BK][BM + 4];
    __shared__ float Bs[BK][BN + 4];
    int dir = blockIdx.z;
    const float* Wx = Wxh + (size_t)(layer*2 + dir) * G4 * Ee;
    const float* bx = bxh + (size_t)(layer*2 + dir) * G4;
    const float* bh = bhh + (size_t)(layer*2 + dir) * G4;
    float* gxd = gx + (size_t)dir * Bb * TS * G4;

    int tid = threadIdx.x;
    int m0 = blockIdx.x * BM;
    int n0 = blockIdx.y * BN;
    int tx = tid & 15, ty = tid >> 4;
    int sm = tid >> 1;           // staging row 0..127
    int sk = (tid & 1) * 8;      // staging k offset 0 or 8

    int m = m0 + sm;
    int b = m >> 8;
    int sl = m & 255;
    int sg = slab0 + sl;
    int t = (dir == 0) ? sg : (Tt - 1 - sg);
    const float* arow0 = nullptr;
    const unsigned short* arow0b = nullptr;
    const unsigned short* arow1b = nullptr;
    if (layer == 0) {
        arow0 = emb + (size_t)tokens[b * Tt + t] * Ee;
    } else {
        arow0b = hprevb + (((size_t)(0 * Bb + b)) * Tt + t) * Dd;              // hL[t]
        arow1b = hprevb + (((size_t)(1 * Bb + b)) * Tt + (Tt - 1 - t)) * Dd;   // hR[T-1-t]
    }
    const float* brow = Wx + (size_t)(n0 + sm) * Ee;

    float acc[8][8];
    #pragma unroll
    for (int i = 0; i < 8; ++i)
        #pragma unroll
        for (int j = 0; j < 8; ++j) acc[i][j] = 0.f;

    for (int k0 = 0; k0 < Ee; k0 += BK) {
        int ka = k0 + sk;
        float4 a0, a1, b0, b1;
        if (layer == 0) {
            a0 = *(const float4*)(arow0 + ka);
            a1 = *(const float4*)(arow0 + ka + 4);
        } else {
            // 8-elem bf16 chunk; ka%8==0, Dd%8==0 -> never crosses concat seam
            const unsigned short* p = (ka < Dd) ? (arow0b + ka) : (arow1b + (ka - Dd));
            uint4 r = *(const uint4*)p;
            a0.x = bflo(r.x); a0.y = bfhi(r.x); a0.z = bflo(r.y); a0.w = bfhi(r.y);
            a1.x = bflo(r.z); a1.y = bfhi(r.z); a1.z = bflo(r.w); a1.w = bfhi(r.w);
        }
        b0 = *(const float4*)(brow + ka);
        b1 = *(const float4*)(brow + ka + 4);
        __syncthreads();
        As[sk+0][sm] = a0.x; As[sk+1][sm] = a0.y; As[sk+2][sm] = a0.z; As[sk+3][sm] = a0.w;
        As[sk+4][sm] = a1.x; As[sk+5][sm] = a1.y; As[sk+6][sm] = a1.z; As[sk+7][sm] = a1.w;
        Bs[sk+0][sm] = b0.x; Bs[sk+1][sm] = b0.y; Bs[sk+2][sm] = b0.z; Bs[sk+3][sm] = b0.w;
        Bs[sk+4][sm] = b1.x; Bs[sk+5][sm] = b1.y; Bs[sk+6][sm] = b1.z; Bs[sk+7][sm] = b1.w;
        __syncthreads();
        #pragma unroll
        for (int k = 0; k < BK; ++k) {
            float a[8], bbv[8];
            *(float4*)&a[0]   = *(const float4*)&As[k][ty*8];
            *(float4*)&a[4]   = *(const float4*)&As[k][ty*8+4];
            *(float4*)&bbv[0] = *(const float4*)&Bs[k][tx*8];
            *(float4*)&bbv[4] = *(const float4*)&Bs[k][tx*8+4];
            #pragma unroll
            for (int i = 0; i < 8; ++i)
                #pragma unroll
                for (int j = 0; j < 8; ++j)
                    acc[i][j] = fmaf(a[i], bbv[j], acc[i][j]);
        }
    }
    float bsum[8];
    #pragma unroll
    for (int j = 0; j < 8; ++j) {
        int n = n0 + tx*8 + j;
        bsum[j] = bx[n] + bh[n];
    }
    #pragma unroll
    for (int i = 0; i < 8; ++i) {
        int mm = m0 + ty*8 + i;
        int bo = mm >> 8;
        int so = mm & 255;
        float* orow = gxd + (((size_t)bo * TS + so) * G4) + n0 + tx*8;
        float4 o0 = make_float4(acc[i][0]+bsum[0], acc[i][1]+bsum[1], acc[i][2]+bsum[2], acc[i][3]+bsum[3]);
        float4 o1 = make_float4(acc[i][4]+bsum[4], acc[i][5]+bsum[5], acc[i][6]+bsum[6], acc[i][7]+bsum[7]);
        *(float4*)orow     = o0;
        *(float4*)(orow+4) = o1;
    }
}

// ---------------------------------------------------------------------------
// Relaxed software barrier (per dir-group of 128 blocks). NO release/acquire
// cache ops: h-exchange goes through cache-bypassing agent atomics, and
// __syncthreads drains vmcnt(0) before tid0's add, so the counter can be
// fully relaxed. The workgroup acquire fence is a compiler/waitcnt barrier
// only (no buffer_inv). Bounded spin: break -> wrong answer, not a hang.
// ---------------------------------------------------------------------------
__device__ __forceinline__ void group_barrier(unsigned int* cnt, unsigned int target)
{
    __syncthreads();
    if (threadIdx.x == 0) {
        __hip_atomic_fetch_add(cnt, 1u, __ATOMIC_RELAXED, __HIP_MEMORY_SCOPE_AGENT);
        long long spins = 0;
        while (__hip_atomic_load(cnt, __ATOMIC_RELAXED, __HIP_MEMORY_SCOPE_AGENT) < target) {
            __builtin_amdgcn_s_sleep(2);
            if (++spins > (1LL << 25)) break;   // ~2s safety valve
        }
        __builtin_amdgcn_fence(__ATOMIC_ACQUIRE, "workgroup");
    }
    __syncthreads();
}

// ---------------------------------------------------------------------------
// Persistent LSTM scan over TS steps, one relaxed barrier per step.
// 256 WGs x 256 threads, 1 block/CU. WG -> dir = wg>>7, 8 units x 4 gates.
// Whh register-resident. Recurrent h: fp32 parity ping-pong in hping,
// accessed ONLY via relaxed agent atomics (cache-bypassing -> coherent at
// MALL, no fences). Archival h: bf16 hout, normal cached stores (read only
// by later dispatches). c carry in LDS, spilled to cbuf at slab end.
// ---------------------------------------------------------------------------
__global__ __launch_bounds__(256, 1)
void lstm_scan(const float* __restrict__ Whh,        // [L][2][G4][Dd]
               const float* __restrict__ gx,         // [2][Bb][TS][G4]
               float* __restrict__ cbuf,             // [2][Bb][Dd]
               float* __restrict__ hping,            // [2 parity][2 dir][Bb][Dd] fp32
               unsigned short* __restrict__ hout,    // [2][Bb][Tt][Dd] bf16
               unsigned int* __restrict__ barcnt,
               int layer, int slab0, int nsteps, unsigned int base)
{
    __shared__ float hsh[Bb][Dd];        // h_{t-1}, this dir (16 KB)
    __shared__ float gvsh[4][8][Bb];     // [gate][uu][b]
    __shared__ float csh[8][Bb];         // c carry [uu][b]

    int wg = blockIdx.x;
    int dir = wg >> 7;
    int ublk = wg & 127;
    int u0 = ublk * 8;
    int tid = threadIdx.x;
    int wv = tid >> 6;        // gate index (one wave per gate)
    int ln = tid & 63;
    unsigned int* cnt = barcnt + dir * 32;   // 128B-separated counters

    // Whh slice -> registers: rows = gate wv, units u0..u0+7, k = j4*256 + ln*4
    float4 wreg[8][4];
    {
        const float* wbase = Whh + (((size_t)(layer*2 + dir) * G4) + wv*Dd + u0) * Dd;
        #pragma unroll
        for (int rr = 0; rr < 8; ++rr)
            #pragma unroll
            for (int j4 = 0; j4 < 4; ++j4)
                wreg[rr][j4] = *(const float4*)(wbase + (size_t)rr*Dd + j4*256 + ln*4);
    }
    if (tid < 32) {
        int uu = tid >> 2, b = tid & 3;
        csh[uu][b] = (slab0 == 0) ? 0.f : cbuf[(dir*Bb + b)*Dd + u0 + uu];
    }
    // csh touched only by the same (tid<32) threads before the first stage sync.

    for (int s = 0; s < nsteps; ++s) {
        int sg = slab0 + s;
        // stage h_{sg-1} (parity (sg-1)&1) via cache-bypassing atomic loads
        float* hsrc = hping + (size_t)((((sg ^ 1) & 1) * 2 + dir)) * (Bb * Dd);
        #pragma unroll
        for (int q = 0; q < 16; ++q) {
            int f = tid + 256*q;          // dword index 0..4095
            int b = f >> 10, k = f & 1023;
            float v = 0.f;
            if (sg > 0)
                v = __hip_atomic_load(&hsrc[(size_t)b * Dd + k],
                                      __ATOMIC_RELAXED, __HIP_MEMORY_SCOPE_AGENT);
            hsh[b][k] = v;
        }
        __syncthreads();

        // partial dots: 8 rows x 4 batches over this lane's 16 k-positions
        float acc[8][4];
        #pragma unroll
        for (int rr = 0; rr < 8; ++rr)
            #pragma unroll
            for (int b = 0; b < 4; ++b) acc[rr][b] = 0.f;
        #pragma unroll
        for (int j4 = 0; j4 < 4; ++j4) {
            float4 h4[4];
            #pragma unroll
            for (int b = 0; b < 4; ++b)
                h4[b] = *(const float4*)&hsh[b][j4*256 + ln*4];
            #pragma unroll
            for (int rr = 0; rr < 8; ++rr) {
                float4 w4 = wreg[rr][j4];
                #pragma unroll
                for (int b = 0; b < 4; ++b) {
                    acc[rr][b] = fmaf(w4.x, h4[b].x, acc[rr][b]);
                    acc[rr][b] = fmaf(w4.y, h4[b].y, acc[rr][b]);
                    acc[rr][b] = fmaf(w4.z, h4[b].z, acc[rr][b]);
                    acc[rr][b] = fmaf(w4.w, h4[b].w, acc[rr][b]);
                }
            }
        }
        // 64-lane butterfly reduction
        #pragma unroll
        for (int off = 32; off > 0; off >>= 1)
            #pragma unroll
            for (int rr = 0; rr < 8; ++rr)
                #pragma unroll
                for (int b = 0; b < 4; ++b)
                    acc[rr][b] += __shfl_xor(acc[rr][b], off, 64);
        if (ln < 32) {
            int rr = ln >> 2, b = ln & 3;
            float gxv = gx[(((size_t)(dir*Bb + b))*TS + s)*G4 + wv*Dd + u0 + rr];
            gvsh[wv][rr][b] = acc[rr][b] + gxv;
        }
        __syncthreads();

        if (tid < 32) {
            int uu = tid >> 2, b = tid & 3;
            float xi = gvsh[0][uu][b];
            float xg = gvsh[1][uu][b];
            float xf = gvsh[2][uu][b];
            float xo = gvsh[3][uu][b];
            float iv = 1.f / (1.f + expf(-xi));
            float gg = tanhf(xg);
            float fv = 1.f / (1.f + expf(-xf));
            float ov = 1.f / (1.f + expf(-xo));
            float c = fv * csh[uu][b] + iv * gg;
            float h = ov * tanhf(c);
            csh[uu][b] = c;
            __hip_atomic_store(&hping[((size_t)((sg & 1) * 2 + dir) * Bb + b) * Dd + u0 + uu],
                               h, __ATOMIC_RELAXED, __HIP_MEMORY_SCOPE_AGENT);
            hout[(((size_t)(dir*Bb + b))*Tt + sg)*Dd + u0 + uu] = f2bf(h);
        }
        group_barrier(cnt, base + (unsigned int)(s + 1) * 128u);
    }
    if (tid < 32) {
        int uu = tid >> 2, b = tid & 3;
        cbuf[(dir*Bb + b)*Dd + u0 + uu] = csh[uu][b];
    }
}

// ---------------------------------------------------------------------------
// Tail: attention + projection (hfin is bf16)
// ---------------------------------------------------------------------------
__global__ __launch_bounds__(256)
void attn_w_kernel(const unsigned short* __restrict__ hfin, float* __restrict__ w)
{
    int b = blockIdx.x >> 4;
    int t0 = (blockIdx.x & 15) * 256;
    __shared__ float hL[Dd], hR[Dd];
    for (int i = threadIdx.x; i < Dd; i += 256) {
        hL[i] = bf1(hfin[(((size_t)0*Bb + b)*Tt + (Tt-1))*Dd + i]);
        hR[i] = bf1(hfin[(((size_t)1*Bb + b)*Tt + (Tt-1))*Dd + i]);
    }
    __syncthreads();
    int t = t0 + threadIdx.x;
    const unsigned short* rL = hfin + (((size_t)0*Bb + b)*Tt + t)*Dd;
    const unsigned short* rR = hfin + (((size_t)1*Bb + b)*Tt + t)*Dd;
    float acc = 0.f;
    for (int k = 0; k < Dd; k += 8) {
        uint4 a = *(const uint4*)(rL + k);
        uint4 c = *(const uint4*)(rR + k);
        acc += bflo(a.x)*hL[k]   + bfhi(a.x)*hL[k+1] + bflo(a.y)*hL[k+2] + bfhi(a.y)*hL[k+3];
        acc += bflo(a.z)*hL[k+4] + bfhi(a.z)*hL[k+5] + bflo(a.w)*hL[k+6] + bfhi(a.w)*hL[k+7];
        acc += bflo(c.x)*hR[k]   + bfhi(c.x)*hR[k+1] + bflo(c.y)*hR[k+2] + bfhi(c.y)*hR[k+3];
        acc += bflo(c.z)*hR[k+4] + bfhi(c.z)*hR[k+5] + bflo(c.w)*hR[k+6] + bfhi(c.w)*hR[k+7];
    }
    w[b*Tt + t] = acc * (1.0f / 64.0f);   // 1/sqrt(4096)
}

__global__ __launch_bounds__(256)
void softmax_kernel(const float* __restrict__ w, float* __restrict__ att)
{
    int b = blockIdx.x;
    __shared__ float red[256];
    int tid = threadIdx.x;
    float mx = -1e30f;
    for (int t = tid; t < Tt; t += 256) mx = fmaxf(mx, w[b*Tt + t]);
    red[tid] = mx; __syncthreads();
    for (int st = 128; st > 0; st >>= 1) {
        if (tid < st) red[tid] = fmaxf(red[tid], red[tid + st]);
        __syncthreads();
    }
    mx = red[0]; __syncthreads();
    float sum = 0.f;
    for (int t = tid; t < Tt; t += 256) sum += expf(w[b*Tt + t] - mx);
    red[tid] = sum; __syncthreads();
    for (int st = 128; st > 0; st >>= 1) {
        if (tid < st) red[tid] += red[tid + st];
        __syncthreads();
    }
    sum = red[0];
    float inv = 1.f / sum;
    for (int t = tid; t < Tt; t += 256) att[b*Tt + t] = expf(w[b*Tt + t] - mx) * inv;
}

__global__ __launch_bounds__(256)
void ctxt_kernel(const float* __restrict__ att, const unsigned short* __restrict__ hfin,
                 float* __restrict__ ctxt)
{
    int dir = blockIdx.x >> 4;
    int b = (blockIdx.x >> 2) & 3;
    int k0 = (blockIdx.x & 3) * 256;
    __shared__ float attS[Tt];
    for (int i = threadIdx.x; i < Tt; i += 256) attS[i] = att[b*Tt + i];
    __syncthreads();
    int k = k0 + threadIdx.x;
    const unsigned short* base = hfin + (((size_t)dir*Bb + b)*Tt)*Dd + k;
    float acc = 0.f;
    for (int t = 0; t < Tt; ++t)
        acc = fmaf(attS[t], bf1(base[(size_t)t * Dd]), acc);
    ctxt[((size_t)dir*Bb + b)*Dd + k] = acc;
}

__global__ __launch_bounds__(256)
void final_kernel(const float* __restrict__ ctxt, const float* __restrict__ WcyL,
                  const float* __restrict__ WcyR, float* __restrict__ out)
{
    __shared__ float red[256];
    int tid = threadIdx.x;
    int g = tid >> 5;
    int l = tid & 31;
    int b = g >> 1, m = g & 1;
    float acc = 0.f;
    for (int k = l; k < Dd; k += 32)
        acc += WcyL[m*Dd + k] * ctxt[((size_t)0*Bb + b)*Dd + k]
             + WcyR[m*Dd + k] * ctxt[((size_t)1*Bb + b)*Dd + k];
    red[tid] = acc; __syncthreads();
    for (int st = 16; st > 0; st >>= 1) {
        if (l < st) red[tid] += red[tid + st];
        __syncthreads();
    }
    if (l == 0) out[b*2 + m] = red[tid];
}

// Diagnostic sentinel: distinguishable failure modes in absmax.
__global__ void sentinel_kernel(float* out, int n, float v)
{
    int i = blockIdx.x * blockDim.x + threadIdx.x;
    if (i < n) out[i] = v;
}

// ---------------------------------------------------------------------------
extern "C" void kernel_launch(void* const* d_in, const int* in_sizes, int n_in,
                              void* d_out, int out_size, void* d_ws, size_t ws_size,
                              hipStream_t stream)
{
    const int*   tokens = (const int*)d_in[0];
    const float* emb  = (const float*)d_in[1];
    const float* Wxh  = (const float*)d_in[2];
    const float* Whh  = (const float*)d_in[3];
    const float* bxh  = (const float*)d_in[4];
    const float* bhh  = (const float*)d_in[5];
    const float* WcyL = (const float*)d_in[6];
    const float* WcyR = (const float*)d_in[7];
    float* out = (float*)d_out;

    // Workspace layout (floats), then bf16 h arrays, then barrier counters.
    const size_t gx_f    = (size_t)2 * Bb * TS * G4;        // 8,388,608
    const size_t hping_f = (size_t)2 * 2 * Bb * Dd;         // 16,384
    const size_t cbuf_f  = (size_t)2 * Bb * Dd;             // 8,192
    const size_t wbuf_f  = (size_t)Bb * Tt;                 // 16,384
    const size_t attb_f  = (size_t)Bb * Tt;                 // 16,384
    const size_t ctxt_f  = (size_t)2 * Bb * Dd;             // 8,192
    const size_t h_e     = (size_t)2 * Bb * Tt * Dd;        // bf16 elems each
    const size_t need_bytes = (gx_f + hping_f + cbuf_f + wbuf_f + attb_f + ctxt_f) * 4
                            + 2 * h_e * 2 + 256;            // ~168 MiB
    if (ws_size < need_bytes) {
        sentinel_kernel<<<1, 64, 0, stream>>>(out, out_size, 1.0e6f);  // ws too small
        return;
    }
    float* ws    = (float*)d_ws;
    float* gx    = ws;
    float* hping = gx + gx_f;
    float* cbuf  = hping + hping_f;
    float* wbuf  = cbuf + cbuf_f;
    float* attb  = wbuf + wbuf_f;
    float* ctxt  = attb + attb_f;
    unsigned short* hA = (unsigned short*)(ctxt + ctxt_f);  // layer0 h bf16
    unsigned short* hB = hA + h_e;                          // layer1 h bf16
    unsigned int* barcnt = (unsigned int*)(hB + h_e);       // 2 x 32 uints

    // zero the barrier counters (ws is re-poisoned before every call)
    hipMemsetAsync(barcnt, 0, 256, stream);

    unsigned int launch_idx = 0;
    for (int layer = 0; layer < 2; ++layer) {
        unsigned short* hout = (layer == 0) ? hA : hB;
        for (int slab = 0; slab < NSLAB; ++slab) {
            int slab0 = slab * TS;
            gemm_gx<<<dim3(8, 32, 2), 256, 0, stream>>>(
                Wxh, bxh, bhh, tokens, emb, hA, gx, layer, slab0);
            unsigned int base = launch_idx * (unsigned int)TS * 128u;
            lstm_scan<<<256, 256, 0, stream>>>(Whh, gx, cbuf, hping, hout,
                                               barcnt, layer, slab0, TS, base);
            ++launch_idx;
        }
    }
    attn_w_kernel<<<Bb*16, 256, 0, stream>>>(hB, wbuf);
    softmax_kernel<<<Bb, 256, 0, stream>>>(wbuf, attb);
    ctxt_kernel<<<32, 256, 0, stream>>>(attb, hB, ctxt);
    final_kernel<<<1, 256, 0, stream>>>(ctxt, WcyL, WcyR, out);
}